// Round 1
// baseline (273.717 us; speedup 1.0000x reference)
//
#include <hip/hip_runtime.h>
#include <math.h>

#define S 256
#define HD 768
#define RR 256
#define NSPAN 2020
#define BB 8

// ---------------- K1: logits[b*S+s] = dot(H[b,s,:], w_attn) + b_attn ----------------
__global__ __launch_bounds__(64) void k_logits(const float* __restrict__ H,
                                               const float* __restrict__ w_attn,
                                               const float* __restrict__ b_attn,
                                               float* __restrict__ logits) {
    int row = blockIdx.x;            // 0 .. B*S-1
    int lane = threadIdx.x;          // 64
    const float* h = H + (size_t)row * HD;
    float acc = 0.f;
    for (int k = lane; k < HD; k += 64) acc += h[k] * w_attn[k];
    for (int off = 32; off; off >>= 1) acc += __shfl_down(acc, off);
    if (lane == 0) logits[row] = acc + b_attn[0];
}

// ---------------- K2: EW[w][r] = sum_k W_width[w,k] * W_span[2304+k, r] ----------------
__global__ __launch_bounds__(256) void k_ew(const float* __restrict__ W_width,
                                            const float* __restrict__ W_span,
                                            float* __restrict__ EW) {
    int w = blockIdx.x;   // 0..8
    int r = threadIdx.x;  // 0..255
    float acc = 0.f;
    for (int k = 0; k < 32; ++k)
        acc += W_width[w * 32 + k] * W_span[(size_t)(2304 + k) * RR + r];
    EW[w * RR + r] = acc;
}

// ---------------- K3: h_mean[b,h] = sum_s H[b,s,h]*mask / clip(sum mask,1) ----------------
__global__ __launch_bounds__(256) void k_hmean(const float* __restrict__ H,
                                               const float* __restrict__ mask,
                                               float* __restrict__ hmean) {
    int b = blockIdx.x;
    int t = threadIdx.x;
    for (int h = t; h < HD; h += 256) {
        float acc = 0.f, ms = 0.f;
        for (int s2 = 0; s2 < S; ++s2) {
            float m = mask[b * S + s2];
            acc += H[((size_t)b * S + s2) * HD + h] * m;
            ms += m;
        }
        float len = ms < 1.f ? 1.f : ms;
        hmean[b * HD + h] = acc / len;
    }
}

// ---------------- K4: null heads ----------------
__global__ __launch_bounds__(256) void k_null(const float* __restrict__ hmean,
                                              const float* __restrict__ W_nasp,
                                              const float* __restrict__ b_nasp,
                                              const float* __restrict__ W_nopn,
                                              const float* __restrict__ b_nopn,
                                              float* __restrict__ out_nasp,
                                              float* __restrict__ out_nopn) {
    __shared__ float hm[HD];
    int b = blockIdx.x;
    int r = threadIdx.x;
    for (int h = r; h < HD; h += 256) hm[h] = hmean[b * HD + h];
    __syncthreads();
    float a = 0.f, o = 0.f;
    for (int h = 0; h < HD; ++h) {
        float x = hm[h];
        a += x * W_nasp[(size_t)h * RR + r];
        o += x * W_nopn[(size_t)h * RR + r];
    }
    out_nasp[b * RR + r] = tanhf(a + b_nasp[r]);
    out_nopn[b * RR + r] = tanhf(o + b_nopn[r]);
}

// ---------------- K5: P GEMM.  A = H (2048 x 768).  Wcat column n: chunk c = n>>8,
// r = n&255, element (h,n) at W_span[(c*768 + h)*256 + r].
// P stored as 3 chunks of (2048 x 256): P[c*524288 + m*256 + r].
#define BM 64
#define BN 64
#define BK 16
__global__ __launch_bounds__(256) void k_gemm(const float* __restrict__ A,
                                              const float* __restrict__ Wspan,
                                              float* __restrict__ P) {
    __shared__ float As[BM][BK + 1];   // padded: conflict-free write & broadcast read
    __shared__ float Bs[BK][BN];       // 2-way on read = free
    int m0 = blockIdx.x * BM;
    int n0 = blockIdx.y * BN;
    int tid = threadIdx.x;
    int tx = tid & 15, ty = tid >> 4;
    float acc[4][4] = {{0.f}};

    for (int k0 = 0; k0 < HD; k0 += BK) {
        for (int e = tid; e < BM * BK; e += 256) {
            int row = e >> 4, kk = e & 15;
            As[row][kk] = A[(size_t)(m0 + row) * HD + k0 + kk];
        }
        for (int e = tid; e < BK * BN; e += 256) {
            int kk = e >> 6, nn = e & 63;
            int n = n0 + nn;
            Bs[kk][nn] = Wspan[(size_t)(n >> 8) * 196608 + (size_t)(k0 + kk) * 256 + (n & 255)];
        }
        __syncthreads();
        #pragma unroll
        for (int kk = 0; kk < BK; ++kk) {
            float a0 = As[ty * 4 + 0][kk];
            float a1 = As[ty * 4 + 1][kk];
            float a2 = As[ty * 4 + 2][kk];
            float a3 = As[ty * 4 + 3][kk];
            float b0 = Bs[kk][tx * 4 + 0];
            float b1 = Bs[kk][tx * 4 + 1];
            float b2 = Bs[kk][tx * 4 + 2];
            float b3 = Bs[kk][tx * 4 + 3];
            acc[0][0] += a0 * b0; acc[0][1] += a0 * b1; acc[0][2] += a0 * b2; acc[0][3] += a0 * b3;
            acc[1][0] += a1 * b0; acc[1][1] += a1 * b1; acc[1][2] += a1 * b2; acc[1][3] += a1 * b3;
            acc[2][0] += a2 * b0; acc[2][1] += a2 * b1; acc[2][2] += a2 * b2; acc[2][3] += a2 * b3;
            acc[3][0] += a3 * b0; acc[3][1] += a3 * b1; acc[3][2] += a3 * b2; acc[3][3] += a3 * b3;
        }
        __syncthreads();
    }
    #pragma unroll
    for (int i = 0; i < 4; ++i) {
        int m = m0 + ty * 4 + i;
        #pragma unroll
        for (int j = 0; j < 4; ++j) {
            int n = n0 + tx * 4 + j;
            P[(size_t)(n >> 8) * 524288 + (size_t)m * 256 + (n & 255)] = acc[i][j];
        }
    }
}

// ---------------- K6: span combination ----------------
__global__ __launch_bounds__(256) void k_span(const float* __restrict__ logits,
                                              const float* __restrict__ P,
                                              const float* __restrict__ EW,
                                              const float* __restrict__ b_span,
                                              const float* __restrict__ w_asp,
                                              const float* __restrict__ b_asp,
                                              const float* __restrict__ w_opn,
                                              const float* __restrict__ b_opn,
                                              float* __restrict__ out_repr,
                                              float* __restrict__ out_asp,
                                              float* __restrict__ out_opn) {
    int n = blockIdx.x;
    int b = blockIdx.y;
    int start, end;
    if (n < 1992) {
        start = n >> 3;
        end = start + (n & 7);
    } else {
        int rem = n - 1992;
        int i = 249, c = 7;
        while (rem >= c) { rem -= c; ++i; --c; }
        start = i;
        end = i + rem;
    }
    int w = end - start + 1;

    // softmax over the (<=8) valid window logits — computed redundantly per thread
    float lg[8];
    float m = -INFINITY;
    for (int l = 0; l < w; ++l) {
        lg[l] = logits[b * S + start + l];
        m = fmaxf(m, lg[l]);
    }
    float ssum = 0.f;
    for (int l = 0; l < w; ++l) {
        lg[l] = expf(lg[l] - m);
        ssum += lg[l];
    }
    float inv = 1.f / ssum;

    int r = threadIdx.x;
    const float* P0 = P;
    const float* P1 = P + 524288;
    const float* P2 = P + 2 * 524288;
    size_t baseS = (size_t)b * S;

    float acc = P0[(baseS + start) * RR + r] + P1[(baseS + end) * RR + r]
              + EW[w * RR + r] + b_span[r];
    for (int l = 0; l < w; ++l)
        acc += (lg[l] * inv) * P2[(baseS + start + l) * RR + r];

    float v = fmaxf(acc, 0.f);
    size_t oi = (size_t)b * NSPAN + n;
    out_repr[oi * RR + r] = v;

    float pa = v * w_asp[r];
    float po = v * w_opn[r];
    for (int off = 32; off; off >>= 1) {
        pa += __shfl_down(pa, off);
        po += __shfl_down(po, off);
    }
    __shared__ float sa[4], so[4];
    int lane = r & 63, wv = r >> 6;
    if (lane == 0) { sa[wv] = pa; so[wv] = po; }
    __syncthreads();
    if (r == 0) {
        out_asp[oi] = sa[0] + sa[1] + sa[2] + sa[3] + b_asp[0];
        out_opn[oi] = so[0] + so[1] + so[2] + so[3] + b_opn[0];
    }
}

extern "C" void kernel_launch(void* const* d_in, const int* in_sizes, int n_in,
                              void* d_out, int out_size, void* d_ws, size_t ws_size,
                              hipStream_t stream) {
    const float* H       = (const float*)d_in[0];
    const float* mask    = (const float*)d_in[1];
    const float* W_width = (const float*)d_in[2];
    const float* w_attn  = (const float*)d_in[3];
    const float* b_attn  = (const float*)d_in[4];
    const float* W_span  = (const float*)d_in[5];
    const float* b_span  = (const float*)d_in[6];
    const float* w_asp   = (const float*)d_in[7];
    const float* b_asp   = (const float*)d_in[8];
    const float* w_opn   = (const float*)d_in[9];
    const float* b_opn   = (const float*)d_in[10];
    const float* W_nasp  = (const float*)d_in[11];
    const float* b_nasp  = (const float*)d_in[12];
    const float* W_nopn  = (const float*)d_in[13];
    const float* b_nopn  = (const float*)d_in[14];

    float* out  = (float*)d_out;
    float* repr = out;                                    // B*N*R
    float* asp  = out + (size_t)BB * NSPAN * RR;          // B*N
    float* opn  = asp + (size_t)BB * NSPAN;               // B*N
    float* nasp = opn + (size_t)BB * NSPAN;               // B*R
    float* nopn = nasp + (size_t)BB * RR;                 // B*R

    float* ws     = (float*)d_ws;
    float* logits = ws;               // 2048
    float* hmean  = ws + 2048;        // 6144
    float* EW     = ws + 8192;        // 9*256 = 2304
    float* P      = ws + 10496;       // 3 * 2048*256 = 1,572,864

    k_logits<<<dim3(BB * S), dim3(64), 0, stream>>>(H, w_attn, b_attn, logits);
    k_ew<<<dim3(9), dim3(256), 0, stream>>>(W_width, W_span, EW);
    k_hmean<<<dim3(BB), dim3(256), 0, stream>>>(H, mask, hmean);
    k_null<<<dim3(BB), dim3(256), 0, stream>>>(hmean, W_nasp, b_nasp, W_nopn, b_nopn, nasp, nopn);
    k_gemm<<<dim3(2048 / BM, 768 / BN), dim3(256), 0, stream>>>(H, W_span, P);
    k_span<<<dim3(NSPAN, BB), dim3(256), 0, stream>>>(logits, P, EW, b_span, w_asp, b_asp,
                                                      w_opn, b_opn, repr, asp, opn);
}

// Round 2
// 134.461 us; speedup vs baseline: 2.0357x; 2.0357x over previous
//
#include <hip/hip_runtime.h>
#include <math.h>

#define S 256
#define HD 768
#define RR 256
#define NSPAN 2020
#define BB 8

typedef __attribute__((ext_vector_type(8))) short bf16x8;
typedef __attribute__((ext_vector_type(4))) float f32x4;

__device__ inline ushort f2bf(float x) {
    union { float f; unsigned u; } v; v.f = x;
    unsigned r = v.u + 0x7FFF + ((v.u >> 16) & 1);
    return (ushort)(r >> 16);
}

// ---------------- logits[b*S+s] = dot(H[b,s,:], w_attn) + b_attn ----------------
__global__ __launch_bounds__(64) void k_logits(const float* __restrict__ H,
                                               const float* __restrict__ w_attn,
                                               const float* __restrict__ b_attn,
                                               float* __restrict__ logits) {
    int row = blockIdx.x;
    int lane = threadIdx.x;
    const float* h = H + (size_t)row * HD;
    float acc = 0.f;
    for (int k = lane; k < HD; k += 64) acc += h[k] * w_attn[k];
    for (int off = 32; off; off >>= 1) acc += __shfl_down(acc, off);
    if (lane == 0) logits[row] = acc + b_attn[0];
}

// ---------------- EW[w][r] = sum_k W_width[w,k] * W_span[2304+k, r] ----------------
__global__ __launch_bounds__(256) void k_ew(const float* __restrict__ W_width,
                                            const float* __restrict__ W_span,
                                            float* __restrict__ EW) {
    int w = blockIdx.x;
    int r = threadIdx.x;
    float acc = 0.f;
    for (int k = 0; k < 32; ++k)
        acc += W_width[w * 32 + k] * W_span[(size_t)(2304 + k) * RR + r];
    EW[w * RR + r] = acc;
}

// ---------------- h_mean: grid (B, 12), 64 h-cols per block ----------------
__global__ __launch_bounds__(256) void k_hmean(const float* __restrict__ H,
                                               const float* __restrict__ mask,
                                               float* __restrict__ hmean) {
    int b = blockIdx.x, hb = blockIdx.y;
    int tid = threadIdx.x;
    int sg = tid >> 6, hl = tid & 63;
    int h = hb * 64 + hl;
    float acc = 0.f;
    for (int s2 = sg; s2 < S; s2 += 4)
        acc += H[((size_t)b * S + s2) * HD + h] * mask[b * S + s2];
    __shared__ float red[4][64];
    red[sg][hl] = acc;
    __syncthreads();
    if (sg == 0) {
        float ms = 0.f;
        for (int s2 = 0; s2 < S; ++s2) ms += mask[b * S + s2];
        float len = ms < 1.f ? 1.f : ms;
        hmean[b * HD + h] = (red[0][hl] + red[1][hl] + red[2][hl] + red[3][hl]) / len;
    }
}

// ---------------- null heads ----------------
__global__ __launch_bounds__(256) void k_null(const float* __restrict__ hmean,
                                              const float* __restrict__ W_nasp,
                                              const float* __restrict__ b_nasp,
                                              const float* __restrict__ W_nopn,
                                              const float* __restrict__ b_nopn,
                                              float* __restrict__ out_nasp,
                                              float* __restrict__ out_nopn) {
    __shared__ float hm[HD];
    int b = blockIdx.x;
    int r = threadIdx.x;
    for (int h = r; h < HD; h += 256) hm[h] = hmean[b * HD + h];
    __syncthreads();
    float a = 0.f, o = 0.f;
    for (int h = 0; h < HD; ++h) {
        float x = hm[h];
        a += x * W_nasp[(size_t)h * RR + r];
        o += x * W_nopn[(size_t)h * RR + r];
    }
    out_nasp[b * RR + r] = tanhf(a + b_nasp[r]);
    out_nopn[b * RR + r] = tanhf(o + b_nopn[r]);
}

// ---------------- H fp32 -> bf16 (row-major, unchanged layout) ----------------
__global__ __launch_bounds__(256) void k_cvtH(const float* __restrict__ H,
                                              ushort* __restrict__ Hb) {
    int i = blockIdx.x * 256 + threadIdx.x;   // one float4 per thread
    float4 v = *(const float4*)(H + (size_t)i * 4);
    ushort4 o;
    o.x = f2bf(v.x); o.y = f2bf(v.y); o.z = f2bf(v.z); o.w = f2bf(v.w);
    *(ushort4*)(Hb + (size_t)i * 4) = o;
}

// ---------------- W_span[0:2304]  ->  Wt[n][h] bf16 (transposed) ----------------
// Wt[(c*256 + r)*768 + h] = W_span[(c*768 + h)*256 + r]
__global__ __launch_bounds__(256) void k_cvtW(const float* __restrict__ Wspan,
                                              ushort* __restrict__ Wt) {
    __shared__ float tile[64][65];
    int hb = blockIdx.x, rb = blockIdx.y, c = blockIdx.z;
    int tid = threadIdx.x;
    for (int e = tid; e < 4096; e += 256) {
        int hl = e >> 6, rl = e & 63;
        tile[hl][rl] = Wspan[(size_t)(c * 768 + hb * 64 + hl) * 256 + rb * 64 + rl];
    }
    __syncthreads();
    for (int e = tid; e < 4096; e += 256) {
        int rl = e >> 6, hl = e & 63;
        Wt[(size_t)(c * 256 + rb * 64 + rl) * 768 + hb * 64 + hl] = f2bf(tile[hl][rl]);
    }
}

// ---------------- MFMA GEMM: P[n>>8][m][n&255] = sum_h Hb[m][h] * Wt[n][h] ----------------
#define GBM 64
#define GBN 64
#define GBK 64
__global__ __launch_bounds__(256) void k_gemm_mfma(const ushort* __restrict__ Hb,
                                                   const ushort* __restrict__ Wt,
                                                   float* __restrict__ P) {
    __shared__ __align__(16) char ldsA[GBM * GBK * 2];
    __shared__ __align__(16) char ldsB[GBN * GBK * 2];
    int m0 = blockIdx.x * GBM;
    int n0 = blockIdx.y * GBN;
    int tid = threadIdx.x;
    int wv = tid >> 6, lane = tid & 63;
    int wm = (wv >> 1) * 32, wn = (wv & 1) * 32;

    f32x4 acc[2][2] = {};

    for (int k0 = 0; k0 < HD; k0 += GBK) {
        #pragma unroll
        for (int i = 0; i < 2; ++i) {
            int c8 = tid * 2 + i;            // 8-elem chunk id, 0..511
            int row = c8 >> 3;
            int colb = (c8 & 7) * 16;        // byte offset within 128B row
            int sw = colb ^ ((row & 7) << 4);
            bf16x8 va = *(const bf16x8*)(Hb + (size_t)(m0 + row) * HD + k0 + (c8 & 7) * 8);
            *(bf16x8*)(ldsA + row * 128 + sw) = va;
            bf16x8 vb = *(const bf16x8*)(Wt + (size_t)(n0 + row) * HD + k0 + (c8 & 7) * 8);
            *(bf16x8*)(ldsB + row * 128 + sw) = vb;
        }
        __syncthreads();
        #pragma unroll
        for (int ks = 0; ks < 2; ++ks) {
            int kb = ks * 64 + ((lane >> 4) * 16);   // byte offset of this lane's 8 k-elems
            bf16x8 af[2], bfr[2];
            #pragma unroll
            for (int f = 0; f < 2; ++f) {
                int ar = wm + f * 16 + (lane & 15);
                af[f] = *(const bf16x8*)(ldsA + ar * 128 + (kb ^ ((ar & 7) << 4)));
                int br = wn + f * 16 + (lane & 15);
                bfr[f] = *(const bf16x8*)(ldsB + br * 128 + (kb ^ ((br & 7) << 4)));
            }
            #pragma unroll
            for (int i = 0; i < 2; ++i)
                #pragma unroll
                for (int j = 0; j < 2; ++j)
                    acc[i][j] = __builtin_amdgcn_mfma_f32_16x16x32_bf16(af[i], bfr[j], acc[i][j], 0, 0, 0);
        }
        __syncthreads();
    }

    #pragma unroll
    for (int i = 0; i < 2; ++i) {
        #pragma unroll
        for (int j = 0; j < 2; ++j) {
            int col = n0 + wn + j * 16 + (lane & 15);
            size_t pb = (size_t)(col >> 8) * 524288 + (col & 255);
            #pragma unroll
            for (int rg = 0; rg < 4; ++rg) {
                int row = m0 + wm + i * 16 + (lane >> 4) * 4 + rg;
                P[pb + (size_t)row * 256] = acc[i][j][rg];
            }
        }
    }
}

// ---------------- span combination ----------------
__global__ __launch_bounds__(256) void k_span(const float* __restrict__ logits,
                                              const float* __restrict__ P,
                                              const float* __restrict__ EW,
                                              const float* __restrict__ b_span,
                                              const float* __restrict__ w_asp,
                                              const float* __restrict__ b_asp,
                                              const float* __restrict__ w_opn,
                                              const float* __restrict__ b_opn,
                                              float* __restrict__ out_repr,
                                              float* __restrict__ out_asp,
                                              float* __restrict__ out_opn) {
    int n = blockIdx.x;
    int b = blockIdx.y;
    int start, end;
    if (n < 1992) {
        start = n >> 3;
        end = start + (n & 7);
    } else {
        int rem = n - 1992;
        int i = 249, c = 7;
        while (rem >= c) { rem -= c; ++i; --c; }
        start = i;
        end = i + rem;
    }
    int w = end - start + 1;

    float lg[8];
    float m = -INFINITY;
    for (int l = 0; l < w; ++l) {
        lg[l] = logits[b * S + start + l];
        m = fmaxf(m, lg[l]);
    }
    float ssum = 0.f;
    for (int l = 0; l < w; ++l) {
        lg[l] = expf(lg[l] - m);
        ssum += lg[l];
    }
    float inv = 1.f / ssum;

    int r = threadIdx.x;
    const float* P0 = P;
    const float* P1 = P + 524288;
    const float* P2 = P + 2 * 524288;
    size_t baseS = (size_t)b * S;

    float acc = P0[(baseS + start) * RR + r] + P1[(baseS + end) * RR + r]
              + EW[w * RR + r] + b_span[r];
    for (int l = 0; l < w; ++l)
        acc += (lg[l] * inv) * P2[(baseS + start + l) * RR + r];

    float v = fmaxf(acc, 0.f);
    size_t oi = (size_t)b * NSPAN + n;
    out_repr[oi * RR + r] = v;

    float pa = v * w_asp[r];
    float po = v * w_opn[r];
    for (int off = 32; off; off >>= 1) {
        pa += __shfl_down(pa, off);
        po += __shfl_down(po, off);
    }
    __shared__ float sa[4], so[4];
    int lane = r & 63, wv = r >> 6;
    if (lane == 0) { sa[wv] = pa; so[wv] = po; }
    __syncthreads();
    if (r == 0) {
        out_asp[oi] = sa[0] + sa[1] + sa[2] + sa[3] + b_asp[0];
        out_opn[oi] = so[0] + so[1] + so[2] + so[3] + b_opn[0];
    }
}

extern "C" void kernel_launch(void* const* d_in, const int* in_sizes, int n_in,
                              void* d_out, int out_size, void* d_ws, size_t ws_size,
                              hipStream_t stream) {
    const float* H       = (const float*)d_in[0];
    const float* mask    = (const float*)d_in[1];
    const float* W_width = (const float*)d_in[2];
    const float* w_attn  = (const float*)d_in[3];
    const float* b_attn  = (const float*)d_in[4];
    const float* W_span  = (const float*)d_in[5];
    const float* b_span  = (const float*)d_in[6];
    const float* w_asp   = (const float*)d_in[7];
    const float* b_asp   = (const float*)d_in[8];
    const float* w_opn   = (const float*)d_in[9];
    const float* b_opn   = (const float*)d_in[10];
    const float* W_nasp  = (const float*)d_in[11];
    const float* b_nasp  = (const float*)d_in[12];
    const float* W_nopn  = (const float*)d_in[13];
    const float* b_nopn  = (const float*)d_in[14];

    float* out  = (float*)d_out;
    float* repr = out;
    float* asp  = out + (size_t)BB * NSPAN * RR;
    float* opn  = asp + (size_t)BB * NSPAN;
    float* nasp = opn + (size_t)BB * NSPAN;
    float* nopn = nasp + (size_t)BB * RR;

    float* ws     = (float*)d_ws;
    float* logits = ws;                 // 2048
    float* hmean  = ws + 2048;          // 6144
    float* EW     = ws + 8192;          // 2304
    float* P      = ws + 10496;         // 3 * 524288 fp32
    ushort* Hb    = (ushort*)(P + 3 * 524288);          // 2048*768 bf16
    ushort* Wt    = Hb + (size_t)2048 * 768;            // 768*768 bf16

    k_cvtH<<<dim3(1536), dim3(256), 0, stream>>>(H, Hb);
    k_cvtW<<<dim3(12, 4, 3), dim3(256), 0, stream>>>(W_span, Wt);
    k_logits<<<dim3(BB * S), dim3(64), 0, stream>>>(H, w_attn, b_attn, logits);
    k_ew<<<dim3(9), dim3(256), 0, stream>>>(W_width, W_span, EW);
    k_hmean<<<dim3(BB, 12), dim3(256), 0, stream>>>(H, mask, hmean);
    k_null<<<dim3(BB), dim3(256), 0, stream>>>(hmean, W_nasp, b_nasp, W_nopn, b_nopn, nasp, nopn);
    k_gemm_mfma<<<dim3(2048 / GBM, 768 / GBN), dim3(256), 0, stream>>>(Hb, Wt, P);
    k_span<<<dim3(NSPAN, BB), dim3(256), 0, stream>>>(logits, P, EW, b_span, w_asp, b_asp,
                                                      w_opn, b_opn, repr, asp, opn);
}

// Round 3
// 93.282 us; speedup vs baseline: 2.9343x; 1.4415x over previous
//
#include <hip/hip_runtime.h>
#include <math.h>

#define S 256
#define HD 768
#define RR 256
#define NSPAN 2020
#define BB 8

typedef __attribute__((ext_vector_type(8))) short bf16x8;
typedef __attribute__((ext_vector_type(4))) float f32x4;

__device__ inline ushort f2bf(float x) {
    union { float f; unsigned u; } v; v.f = x;
    unsigned r = v.u + 0x7FFF + ((v.u >> 16) & 1);
    return (ushort)(r >> 16);
}

// ---------------- logits: 4 rows per block, one wave each, float4 loads ----------------
__global__ __launch_bounds__(256) void k_logits(const float* __restrict__ H,
                                                const float* __restrict__ w_attn,
                                                const float* __restrict__ b_attn,
                                                float* __restrict__ logits) {
    int row = blockIdx.x * 4 + (threadIdx.x >> 6);
    int lane = threadIdx.x & 63;
    const float4* h = (const float4*)(H + (size_t)row * HD);
    const float4* w = (const float4*)w_attn;
    float acc = 0.f;
    #pragma unroll
    for (int k = 0; k < 3; ++k) {
        float4 a = h[k * 64 + lane];
        float4 b = w[k * 64 + lane];
        acc += a.x * b.x + a.y * b.y + a.z * b.z + a.w * b.w;
    }
    for (int off = 32; off; off >>= 1) acc += __shfl_down(acc, off);
    if (lane == 0) logits[row] = acc + b_attn[0];
}

// ---------------- EW[w][r] = sum_k W_width[w,k] * W_span[2304+k, r] ----------------
__global__ __launch_bounds__(256) void k_ew(const float* __restrict__ W_width,
                                            const float* __restrict__ W_span,
                                            float* __restrict__ EW) {
    int w = blockIdx.x;
    int r = threadIdx.x;
    float acc = 0.f;
    for (int k = 0; k < 32; ++k)
        acc += W_width[w * 32 + k] * W_span[(size_t)(2304 + k) * RR + r];
    EW[w * RR + r] = acc;
}

// ---------------- h_mean: grid (B, 12), 64 h-cols per block ----------------
__global__ __launch_bounds__(256) void k_hmean(const float* __restrict__ H,
                                               const float* __restrict__ mask,
                                               float* __restrict__ hmean) {
    int b = blockIdx.x, hb = blockIdx.y;
    int tid = threadIdx.x;
    int sg = tid >> 6, hl = tid & 63;
    int h = hb * 64 + hl;
    float acc = 0.f;
    for (int s2 = sg; s2 < S; s2 += 4)
        acc += H[((size_t)b * S + s2) * HD + h] * mask[b * S + s2];
    __shared__ float red[4][64];
    red[sg][hl] = acc;
    __syncthreads();
    if (sg == 0) {
        float ms = 0.f;
        for (int s2 = 0; s2 < S; ++s2) ms += mask[b * S + s2];
        float len = ms < 1.f ? 1.f : ms;
        hmean[b * HD + h] = (red[0][hl] + red[1][hl] + red[2][hl] + red[3][hl]) / len;
    }
}

// ---------------- null heads ----------------
__global__ __launch_bounds__(256) void k_null(const float* __restrict__ hmean,
                                              const float* __restrict__ W_nasp,
                                              const float* __restrict__ b_nasp,
                                              const float* __restrict__ W_nopn,
                                              const float* __restrict__ b_nopn,
                                              float* __restrict__ out_nasp,
                                              float* __restrict__ out_nopn) {
    __shared__ float hm[HD];
    int b = blockIdx.x;
    int r = threadIdx.x;
    for (int h = r; h < HD; h += 256) hm[h] = hmean[b * HD + h];
    __syncthreads();
    float a = 0.f, o = 0.f;
    for (int h = 0; h < HD; ++h) {
        float x = hm[h];
        a += x * W_nasp[(size_t)h * RR + r];
        o += x * W_nopn[(size_t)h * RR + r];
    }
    out_nasp[b * RR + r] = tanhf(a + b_nasp[r]);
    out_nopn[b * RR + r] = tanhf(o + b_nopn[r]);
}

// ---------------- H fp32 -> bf16 ----------------
__global__ __launch_bounds__(256) void k_cvtH(const float* __restrict__ H,
                                              ushort* __restrict__ Hb) {
    int i = blockIdx.x * 256 + threadIdx.x;
    float4 v = *(const float4*)(H + (size_t)i * 4);
    ushort4 o;
    o.x = f2bf(v.x); o.y = f2bf(v.y); o.z = f2bf(v.z); o.w = f2bf(v.w);
    *(ushort4*)(Hb + (size_t)i * 4) = o;
}

// ---------------- W_span[0:2304] -> Wt[n][h] bf16 (transposed) ----------------
__global__ __launch_bounds__(256) void k_cvtW(const float* __restrict__ Wspan,
                                              ushort* __restrict__ Wt) {
    __shared__ float tile[64][65];
    int hb = blockIdx.x, rb = blockIdx.y, c = blockIdx.z;
    int tid = threadIdx.x;
    for (int e = tid; e < 4096; e += 256) {
        int hl = e >> 6, rl = e & 63;
        tile[hl][rl] = Wspan[(size_t)(c * 768 + hb * 64 + hl) * 256 + rb * 64 + rl];
    }
    __syncthreads();
    for (int e = tid; e < 4096; e += 256) {
        int rl = e >> 6, hl = e & 63;
        Wt[(size_t)(c * 256 + rb * 64 + rl) * 768 + hb * 64 + hl] = f2bf(tile[hl][rl]);
    }
}

// ---------------- MFMA GEMM ----------------
#define GBM 64
#define GBN 64
#define GBK 64
__global__ __launch_bounds__(256) void k_gemm_mfma(const ushort* __restrict__ Hb,
                                                   const ushort* __restrict__ Wt,
                                                   float* __restrict__ P) {
    __shared__ __align__(16) char ldsA[GBM * GBK * 2];
    __shared__ __align__(16) char ldsB[GBN * GBK * 2];
    int m0 = blockIdx.x * GBM;
    int n0 = blockIdx.y * GBN;
    int tid = threadIdx.x;
    int wv = tid >> 6, lane = tid & 63;
    int wm = (wv >> 1) * 32, wn = (wv & 1) * 32;

    f32x4 acc[2][2] = {};

    for (int k0 = 0; k0 < HD; k0 += GBK) {
        #pragma unroll
        for (int i = 0; i < 2; ++i) {
            int c8 = tid * 2 + i;
            int row = c8 >> 3;
            int colb = (c8 & 7) * 16;
            int sw = colb ^ ((row & 7) << 4);
            bf16x8 va = *(const bf16x8*)(Hb + (size_t)(m0 + row) * HD + k0 + (c8 & 7) * 8);
            *(bf16x8*)(ldsA + row * 128 + sw) = va;
            bf16x8 vb = *(const bf16x8*)(Wt + (size_t)(n0 + row) * HD + k0 + (c8 & 7) * 8);
            *(bf16x8*)(ldsB + row * 128 + sw) = vb;
        }
        __syncthreads();
        #pragma unroll
        for (int ks = 0; ks < 2; ++ks) {
            int kb = ks * 64 + ((lane >> 4) * 16);
            bf16x8 af[2], bfr[2];
            #pragma unroll
            for (int f = 0; f < 2; ++f) {
                int ar = wm + f * 16 + (lane & 15);
                af[f] = *(const bf16x8*)(ldsA + ar * 128 + (kb ^ ((ar & 7) << 4)));
                int br = wn + f * 16 + (lane & 15);
                bfr[f] = *(const bf16x8*)(ldsB + br * 128 + (kb ^ ((br & 7) << 4)));
            }
            #pragma unroll
            for (int i = 0; i < 2; ++i)
                #pragma unroll
                for (int j = 0; j < 2; ++j)
                    acc[i][j] = __builtin_amdgcn_mfma_f32_16x16x32_bf16(af[i], bfr[j], acc[i][j], 0, 0, 0);
        }
        __syncthreads();
    }

    #pragma unroll
    for (int i = 0; i < 2; ++i) {
        #pragma unroll
        for (int j = 0; j < 2; ++j) {
            int col = n0 + wn + j * 16 + (lane & 15);
            size_t pb = (size_t)(col >> 8) * 524288 + (col & 255);
            #pragma unroll
            for (int rg = 0; rg < 4; ++rg) {
                int row = m0 + wm + i * 16 + (lane >> 4) * 4 + rg;
                P[pb + (size_t)row * 256] = acc[i][j][rg];
            }
        }
    }
}

// ---------------- span combination: one block per (b, start), all widths ----------------
__global__ __launch_bounds__(256) void k_span2(const float* __restrict__ logits,
                                               const float* __restrict__ P,
                                               const float* __restrict__ EW,
                                               const float* __restrict__ b_span,
                                               const float* __restrict__ w_asp,
                                               const float* __restrict__ b_asp,
                                               const float* __restrict__ w_opn,
                                               const float* __restrict__ b_opn,
                                               float* __restrict__ out_repr,
                                               float* __restrict__ out_asp,
                                               float* __restrict__ out_opn) {
    int start = blockIdx.x;          // 0..255
    int b = blockIdx.y;
    int nw = 256 - start; if (nw > 8) nw = 8;
    int r = threadIdx.x;

    // span index base for (start, j): contiguous in j
    int nbase;
    if (start <= 248) nbase = start * 8;
    else { int t = start - 249; nbase = 1992 + 7 * t - (t * (t - 1)) / 2; }

    // shared-shift softmax prefix (softmax is shift-invariant -> one max M)
    float E[8], inv[8];
    {
        float lg[8];
        float M = -INFINITY;
        for (int l = 0; l < nw; ++l) {
            lg[l] = logits[b * S + start + l];
            M = fmaxf(M, lg[l]);
        }
        float run = 0.f;
        for (int l = 0; l < nw; ++l) {
            E[l] = __expf(lg[l] - M);
            run += E[l];
            inv[l] = 1.f / run;
        }
    }

    const float* P0 = P;
    const float* P1 = P + 524288;
    const float* P2 = P + 2 * 524288;
    size_t base = ((size_t)b * S + start) * RR + r;

    float p0 = P0[base];
    float bs = b_span[r];
    float num = 0.f;

    __shared__ float vbuf[8][256];

    for (int j = 0; j < nw; ++j) {
        num += E[j] * P2[base + (size_t)j * RR];
        float pre = p0 + P1[base + (size_t)j * RR] + num * inv[j]
                  + EW[(j + 1) * RR + r] + bs;
        float v = fmaxf(pre, 0.f);
        vbuf[j][r] = v;
        out_repr[((size_t)b * NSPAN + nbase + j) * RR + r] = v;
    }
    __syncthreads();

    // asp/opn: span j handled by 32-lane group (j = tid>>5)
    int j = r >> 5, c = r & 31;
    if (j < nw) {
        float pa = 0.f, po = 0.f;
        #pragma unroll
        for (int u = 0; u < 8; ++u) {
            int rr = u * 32 + c;                 // bank-conflict-free
            float v = vbuf[j][rr];
            pa += v * w_asp[rr];
            po += v * w_opn[rr];
        }
        #pragma unroll
        for (int off = 16; off; off >>= 1) {
            pa += __shfl_down(pa, off, 32);
            po += __shfl_down(po, off, 32);
        }
        if (c == 0) {
            size_t oi = (size_t)b * NSPAN + nbase + j;
            out_asp[oi] = pa + b_asp[0];
            out_opn[oi] = po + b_opn[0];
        }
    }
}

extern "C" void kernel_launch(void* const* d_in, const int* in_sizes, int n_in,
                              void* d_out, int out_size, void* d_ws, size_t ws_size,
                              hipStream_t stream) {
    const float* H       = (const float*)d_in[0];
    const float* mask    = (const float*)d_in[1];
    const float* W_width = (const float*)d_in[2];
    const float* w_attn  = (const float*)d_in[3];
    const float* b_attn  = (const float*)d_in[4];
    const float* W_span  = (const float*)d_in[5];
    const float* b_span  = (const float*)d_in[6];
    const float* w_asp   = (const float*)d_in[7];
    const float* b_asp   = (const float*)d_in[8];
    const float* w_opn   = (const float*)d_in[9];
    const float* b_opn   = (const float*)d_in[10];
    const float* W_nasp  = (const float*)d_in[11];
    const float* b_nasp  = (const float*)d_in[12];
    const float* W_nopn  = (const float*)d_in[13];
    const float* b_nopn  = (const float*)d_in[14];

    float* out  = (float*)d_out;
    float* repr = out;
    float* asp  = out + (size_t)BB * NSPAN * RR;
    float* opn  = asp + (size_t)BB * NSPAN;
    float* nasp = opn + (size_t)BB * NSPAN;
    float* nopn = nasp + (size_t)BB * RR;

    float* ws     = (float*)d_ws;
    float* logits = ws;                 // 2048
    float* hmean  = ws + 2048;          // 6144
    float* EW     = ws + 8192;          // 2304
    float* P      = ws + 10496;         // 3 * 524288 fp32
    ushort* Hb    = (ushort*)(P + 3 * 524288);          // 2048*768 bf16
    ushort* Wt    = Hb + (size_t)2048 * 768;            // 768*768 bf16

    k_cvtH<<<dim3(1536), dim3(256), 0, stream>>>(H, Hb);
    k_cvtW<<<dim3(12, 4, 3), dim3(256), 0, stream>>>(W_span, Wt);
    k_logits<<<dim3(512), dim3(256), 0, stream>>>(H, w_attn, b_attn, logits);
    k_ew<<<dim3(9), dim3(256), 0, stream>>>(W_width, W_span, EW);
    k_hmean<<<dim3(BB, 12), dim3(256), 0, stream>>>(H, mask, hmean);
    k_null<<<dim3(BB), dim3(256), 0, stream>>>(hmean, W_nasp, b_nasp, W_nopn, b_nopn, nasp, nopn);
    k_gemm_mfma<<<dim3(2048 / GBM, 768 / GBN), dim3(256), 0, stream>>>(Hb, Wt, P);
    k_span2<<<dim3(S, BB), dim3(256), 0, stream>>>(logits, P, EW, b_span, w_asp, b_asp,
                                                   w_opn, b_opn, repr, asp, opn);
}

// Round 4
// 80.683 us; speedup vs baseline: 3.3925x; 1.1562x over previous
//
#include <hip/hip_runtime.h>
#include <math.h>

#define S 256
#define HD 768
#define RR 256
#define NSPAN 2020
#define BB 8

typedef __attribute__((ext_vector_type(8))) short bf16x8;
typedef __attribute__((ext_vector_type(4))) float f32x4;

__device__ inline ushort f2bf(float x) {
    union { float f; unsigned u; } v; v.f = x;
    unsigned r = v.u + 0x7FFF + ((v.u >> 16) & 1);
    return (ushort)(r >> 16);
}

// ---------------- k_prep: H -> bf16 AND logits, one pass over H ----------------
// 4 rows per block (one per wave); each lane holds 12 floats (3 float4).
__global__ __launch_bounds__(256) void k_prep(const float* __restrict__ H,
                                              const float* __restrict__ w_attn,
                                              const float* __restrict__ b_attn,
                                              ushort* __restrict__ Hb,
                                              float* __restrict__ logits) {
    int wv = threadIdx.x >> 6, lane = threadIdx.x & 63;
    int row = blockIdx.x * 4 + wv;
    const float4* h4 = (const float4*)(H + (size_t)row * HD);
    const float4* w4 = (const float4*)w_attn;
    float acc = 0.f;
    #pragma unroll
    for (int k = 0; k < 3; ++k) {
        float4 a = h4[k * 64 + lane];
        float4 w = w4[k * 64 + lane];
        acc += a.x * w.x + a.y * w.y + a.z * w.z + a.w * w.w;
        ushort4 o;
        o.x = f2bf(a.x); o.y = f2bf(a.y); o.z = f2bf(a.z); o.w = f2bf(a.w);
        *(ushort4*)(Hb + (size_t)row * HD + k * 256 + lane * 4) = o;
    }
    for (int off = 32; off; off >>= 1) acc += __shfl_down(acc, off);
    if (lane == 0) logits[row] = acc + b_attn[0];
}

// ---------------- W_span[0:2304] -> Wt[n][h] bf16 (transposed) ----------------
__global__ __launch_bounds__(256) void k_cvtW(const float* __restrict__ Wspan,
                                              ushort* __restrict__ Wt) {
    __shared__ float tile[64][65];
    int hb = blockIdx.x, rb = blockIdx.y, c = blockIdx.z;
    int tid = threadIdx.x;
    for (int e = tid; e < 4096; e += 256) {
        int hl = e >> 6, rl = e & 63;
        tile[hl][rl] = Wspan[(size_t)(c * 768 + hb * 64 + hl) * 256 + rb * 64 + rl];
    }
    __syncthreads();
    for (int e = tid; e < 4096; e += 256) {
        int rl = e >> 6, hl = e & 63;
        Wt[(size_t)(c * 256 + rb * 64 + rl) * 768 + hb * 64 + hl] = f2bf(tile[hl][rl]);
    }
}

// ---------------- h_mean: grid (B, 12), 64 h-cols per block ----------------
__global__ __launch_bounds__(256) void k_hmean(const float* __restrict__ H,
                                               const float* __restrict__ mask,
                                               float* __restrict__ hmean) {
    int b = blockIdx.x, hb = blockIdx.y;
    int tid = threadIdx.x;
    int sg = tid >> 6, hl = tid & 63;
    int h = hb * 64 + hl;
    float acc = 0.f;
    for (int s2 = sg; s2 < S; s2 += 4)
        acc += H[((size_t)b * S + s2) * HD + h] * mask[b * S + s2];
    __shared__ float red[4][64];
    red[sg][hl] = acc;
    __syncthreads();
    if (sg == 0) {
        float ms = 0.f;
        for (int s2 = 0; s2 < S; ++s2) ms += mask[b * S + s2];
        float len = ms < 1.f ? 1.f : ms;
        hmean[b * HD + h] = (red[0][hl] + red[1][hl] + red[2][hl] + red[3][hl]) / len;
    }
}

// ---------------- null heads: grid (B, 8), 32 r-cols x 8 h-chunks ----------------
__global__ __launch_bounds__(256) void k_null2(const float* __restrict__ hmean,
                                               const float* __restrict__ W_nasp,
                                               const float* __restrict__ b_nasp,
                                               const float* __restrict__ W_nopn,
                                               const float* __restrict__ b_nopn,
                                               float* __restrict__ out_nasp,
                                               float* __restrict__ out_nopn) {
    __shared__ float hm[HD];
    __shared__ float ra[8][32], ro[8][32];
    int b = blockIdx.x, rc = blockIdx.y;
    int tid = threadIdx.x;
    int c = tid & 31, hc = tid >> 5;
    int r = rc * 32 + c;
    for (int h = tid; h < HD; h += 256) hm[h] = hmean[b * HD + h];
    __syncthreads();
    float a = 0.f, o = 0.f;
    for (int h = hc * 96; h < hc * 96 + 96; ++h) {
        float x = hm[h];
        a += x * W_nasp[(size_t)h * RR + r];
        o += x * W_nopn[(size_t)h * RR + r];
    }
    ra[hc][c] = a; ro[hc][c] = o;
    __syncthreads();
    if (tid < 32) {
        float sa = 0.f, so = 0.f;
        #pragma unroll
        for (int u = 0; u < 8; ++u) { sa += ra[u][tid]; so += ro[u][tid]; }
        int rr = rc * 32 + tid;
        out_nasp[b * RR + rr] = tanhf(sa + b_nasp[rr]);
        out_nopn[b * RR + rr] = tanhf(so + b_nopn[rr]);
    }
}

// ---------------- MFMA GEMM: 64x128 tile, acc[2][4] per wave ----------------
#define GBM 64
#define GBN 128
#define GBK 64
__global__ __launch_bounds__(256) void k_gemm_mfma(const ushort* __restrict__ Hb,
                                                   const ushort* __restrict__ Wt,
                                                   float* __restrict__ P) {
    __shared__ __align__(16) char ldsA[GBM * 128];   // 8 KB
    __shared__ __align__(16) char ldsB[GBN * 128];   // 16 KB
    int m0 = blockIdx.x * GBM;
    int n0 = blockIdx.y * GBN;
    int tid = threadIdx.x;
    int wv = tid >> 6, lane = tid & 63;
    int wm = (wv >> 1) * 32, wn = (wv & 1) * 64;

    f32x4 acc[2][4] = {};

    for (int k0 = 0; k0 < HD; k0 += GBK) {
        #pragma unroll
        for (int i = 0; i < 2; ++i) {
            int c8 = tid * 2 + i;            // A: 512 chunks
            int row = c8 >> 3;
            int sw = ((c8 & 7) * 16) ^ ((row & 7) << 4);
            bf16x8 va = *(const bf16x8*)(Hb + (size_t)(m0 + row) * HD + k0 + (c8 & 7) * 8);
            *(bf16x8*)(ldsA + row * 128 + sw) = va;
        }
        #pragma unroll
        for (int i = 0; i < 4; ++i) {
            int c8 = tid * 4 + i;            // B: 1024 chunks
            int row = c8 >> 3;
            int sw = ((c8 & 7) * 16) ^ ((row & 7) << 4);
            bf16x8 vb = *(const bf16x8*)(Wt + (size_t)(n0 + row) * HD + k0 + (c8 & 7) * 8);
            *(bf16x8*)(ldsB + row * 128 + sw) = vb;
        }
        __syncthreads();
        #pragma unroll
        for (int ks = 0; ks < 2; ++ks) {
            int kb = ks * 64 + ((lane >> 4) * 16);
            bf16x8 af[2], bfr[4];
            #pragma unroll
            for (int f = 0; f < 2; ++f) {
                int ar = wm + f * 16 + (lane & 15);
                af[f] = *(const bf16x8*)(ldsA + ar * 128 + (kb ^ ((ar & 7) << 4)));
            }
            #pragma unroll
            for (int j = 0; j < 4; ++j) {
                int br = wn + j * 16 + (lane & 15);
                bfr[j] = *(const bf16x8*)(ldsB + br * 128 + (kb ^ ((br & 7) << 4)));
            }
            #pragma unroll
            for (int f = 0; f < 2; ++f)
                #pragma unroll
                for (int j = 0; j < 4; ++j)
                    acc[f][j] = __builtin_amdgcn_mfma_f32_16x16x32_bf16(af[f], bfr[j], acc[f][j], 0, 0, 0);
        }
        __syncthreads();
    }

    #pragma unroll
    for (int f = 0; f < 2; ++f) {
        #pragma unroll
        for (int j = 0; j < 4; ++j) {
            int col = n0 + wn + j * 16 + (lane & 15);
            size_t pb = (size_t)(col >> 8) * 524288 + (col & 255);
            #pragma unroll
            for (int rg = 0; rg < 4; ++rg) {
                int row = m0 + wm + f * 16 + (lane >> 4) * 4 + rg;
                P[pb + (size_t)row * 256] = acc[f][j][rg];
            }
        }
    }
}

// ---------------- span combination: one block per (b, start), EW inline ----------------
__global__ __launch_bounds__(256) void k_span2(const float* __restrict__ logits,
                                               const float* __restrict__ P,
                                               const float* __restrict__ W_width,
                                               const float* __restrict__ W_span,
                                               const float* __restrict__ b_span,
                                               const float* __restrict__ w_asp,
                                               const float* __restrict__ b_asp,
                                               const float* __restrict__ w_opn,
                                               const float* __restrict__ b_opn,
                                               float* __restrict__ out_repr,
                                               float* __restrict__ out_asp,
                                               float* __restrict__ out_opn) {
    int start = blockIdx.x;          // 0..255
    int b = blockIdx.y;
    int nw = 256 - start; if (nw > 8) nw = 8;
    int r = threadIdx.x;

    int nbase;
    if (start <= 248) nbase = start * 8;
    else { int t = start - 249; nbase = 1992 + 7 * t - (t * (t - 1)) / 2; }

    // EW rows 1..8 computed inline (identical fp32 order as the old k_ew)
    float ew[8];
    {
        #pragma unroll
        for (int j = 0; j < 8; ++j) ew[j] = 0.f;
        for (int k = 0; k < 32; ++k) {
            float wsk = W_span[(size_t)(2304 + k) * RR + r];
            #pragma unroll
            for (int j = 0; j < 8; ++j)
                ew[j] += W_width[(j + 1) * 32 + k] * wsk;
        }
    }

    float E[8], inv[8];
    {
        float lg[8];
        float M = -INFINITY;
        for (int l = 0; l < nw; ++l) {
            lg[l] = logits[b * S + start + l];
            M = fmaxf(M, lg[l]);
        }
        float run = 0.f;
        for (int l = 0; l < nw; ++l) {
            E[l] = __expf(lg[l] - M);
            run += E[l];
            inv[l] = 1.f / run;
        }
    }

    const float* P0 = P;
    const float* P1 = P + 524288;
    const float* P2 = P + 2 * 524288;
    size_t base = ((size_t)b * S + start) * RR + r;

    float p0 = P0[base];
    float bs = b_span[r];
    float num = 0.f;

    __shared__ float vbuf[8][256];

    for (int j = 0; j < nw; ++j) {
        num += E[j] * P2[base + (size_t)j * RR];
        float pre = p0 + P1[base + (size_t)j * RR] + num * inv[j]
                  + ew[j] + bs;
        float v = fmaxf(pre, 0.f);
        vbuf[j][r] = v;
        out_repr[((size_t)b * NSPAN + nbase + j) * RR + r] = v;
    }
    __syncthreads();

    int j = r >> 5, c = r & 31;
    if (j < nw) {
        float pa = 0.f, po = 0.f;
        #pragma unroll
        for (int u = 0; u < 8; ++u) {
            int rr = u * 32 + c;
            float v = vbuf[j][rr];
            pa += v * w_asp[rr];
            po += v * w_opn[rr];
        }
        #pragma unroll
        for (int off = 16; off; off >>= 1) {
            pa += __shfl_down(pa, off, 32);
            po += __shfl_down(po, off, 32);
        }
        if (c == 0) {
            size_t oi = (size_t)b * NSPAN + nbase + j;
            out_asp[oi] = pa + b_asp[0];
            out_opn[oi] = po + b_opn[0];
        }
    }
}

extern "C" void kernel_launch(void* const* d_in, const int* in_sizes, int n_in,
                              void* d_out, int out_size, void* d_ws, size_t ws_size,
                              hipStream_t stream) {
    const float* H       = (const float*)d_in[0];
    const float* mask    = (const float*)d_in[1];
    const float* W_width = (const float*)d_in[2];
    const float* w_attn  = (const float*)d_in[3];
    const float* b_attn  = (const float*)d_in[4];
    const float* W_span  = (const float*)d_in[5];
    const float* b_span  = (const float*)d_in[6];
    const float* w_asp   = (const float*)d_in[7];
    const float* b_asp   = (const float*)d_in[8];
    const float* w_opn   = (const float*)d_in[9];
    const float* b_opn   = (const float*)d_in[10];
    const float* W_nasp  = (const float*)d_in[11];
    const float* b_nasp  = (const float*)d_in[12];
    const float* W_nopn  = (const float*)d_in[13];
    const float* b_nopn  = (const float*)d_in[14];

    float* out  = (float*)d_out;
    float* repr = out;
    float* asp  = out + (size_t)BB * NSPAN * RR;
    float* opn  = asp + (size_t)BB * NSPAN;
    float* nasp = opn + (size_t)BB * NSPAN;
    float* nopn = nasp + (size_t)BB * RR;

    float* ws     = (float*)d_ws;
    float* logits = ws;                 // 2048
    float* hmean  = ws + 2048;          // 6144
    float* P      = ws + 8192;          // 3 * 524288 fp32
    ushort* Hb    = (ushort*)(P + 3 * 524288);          // 2048*768 bf16
    ushort* Wt    = Hb + (size_t)2048 * 768;            // 768*768 bf16

    k_prep<<<dim3(512), dim3(256), 0, stream>>>(H, w_attn, b_attn, Hb, logits);
    k_cvtW<<<dim3(12, 4, 3), dim3(256), 0, stream>>>(W_span, Wt);
    k_hmean<<<dim3(BB, 12), dim3(256), 0, stream>>>(H, mask, hmean);
    k_null2<<<dim3(BB, 8), dim3(256), 0, stream>>>(hmean, W_nasp, b_nasp, W_nopn, b_nopn, nasp, nopn);
    k_gemm_mfma<<<dim3(2048 / GBM, 768 / GBN), dim3(256), 0, stream>>>(Hb, Wt, P);
    k_span2<<<dim3(S, BB), dim3(256), 0, stream>>>(logits, P, W_width, W_span, b_span,
                                                   w_asp, b_asp, w_opn, b_opn, repr, asp, opn);
}

// Round 5
// 57.711 us; speedup vs baseline: 4.7429x; 1.3980x over previous
//
#include <hip/hip_runtime.h>
#include <math.h>

#define S 256
#define HD 768
#define RR 256
#define NSPAN 2020
#define BB 8

typedef __attribute__((ext_vector_type(8))) short bf16x8;
typedef __attribute__((ext_vector_type(4))) float f32x4;

__device__ inline ushort f2bf(float x) {
    union { float f; unsigned u; } v; v.f = x;
    unsigned r = v.u + 0x7FFF + ((v.u >> 16) & 1);
    return (ushort)(r >> 16);
}

// =============== k_pre: fused prep(512) | cvtW(144) | hmean(96) | EW(9) ===============
__global__ __launch_bounds__(256) void k_pre(const float* __restrict__ H,
                                             const float* __restrict__ w_attn,
                                             const float* __restrict__ b_attn,
                                             const float* __restrict__ mask,
                                             const float* __restrict__ Wspan,
                                             const float* __restrict__ W_width,
                                             ushort* __restrict__ Hb,
                                             float* __restrict__ logits,
                                             ushort* __restrict__ Wt,
                                             float* __restrict__ hmean,
                                             float* __restrict__ EW) {
    __shared__ __align__(16) char smem[16640];
    int bid = blockIdx.x;
    int tid = threadIdx.x;

    if (bid < 512) {
        // ---- prep: H -> bf16 + logits (4 rows/block, 1 wave each) ----
        int wv = tid >> 6, lane = tid & 63;
        int row = bid * 4 + wv;
        const float4* h4 = (const float4*)(H + (size_t)row * HD);
        const float4* w4 = (const float4*)w_attn;
        float acc = 0.f;
        #pragma unroll
        for (int k = 0; k < 3; ++k) {
            float4 a = h4[k * 64 + lane];
            float4 w = w4[k * 64 + lane];
            acc += a.x * w.x + a.y * w.y + a.z * w.z + a.w * w.w;
            ushort4 o;
            o.x = f2bf(a.x); o.y = f2bf(a.y); o.z = f2bf(a.z); o.w = f2bf(a.w);
            *(ushort4*)(Hb + (size_t)row * HD + k * 256 + lane * 4) = o;
        }
        for (int off = 32; off; off >>= 1) acc += __shfl_down(acc, off);
        if (lane == 0) logits[row] = acc + b_attn[0];
    } else if (bid < 656) {
        // ---- cvtW: W_span[0:2304] -> Wt[n][h] bf16 transposed ----
        float (*tile)[65] = (float(*)[65])smem;
        int idx = bid - 512;
        int hb = idx % 12, rb = (idx / 12) & 3, c = idx / 48;
        for (int e = tid; e < 4096; e += 256) {
            int hl = e >> 6, rl = e & 63;
            tile[hl][rl] = Wspan[(size_t)(c * 768 + hb * 64 + hl) * 256 + rb * 64 + rl];
        }
        __syncthreads();
        for (int e = tid; e < 4096; e += 256) {
            int rl = e >> 6, hl = e & 63;
            Wt[(size_t)(c * 256 + rb * 64 + rl) * 768 + hb * 64 + hl] = f2bf(tile[hl][rl]);
        }
    } else if (bid < 752) {
        // ---- hmean ----
        float (*red)[64] = (float(*)[64])smem;
        int idx = bid - 656;
        int b = idx & 7, hb = idx >> 3;
        int sg = tid >> 6, hl = tid & 63;
        int h = hb * 64 + hl;
        float acc = 0.f;
        for (int s2 = sg; s2 < S; s2 += 4)
            acc += H[((size_t)b * S + s2) * HD + h] * mask[b * S + s2];
        red[sg][hl] = acc;
        __syncthreads();
        if (sg == 0) {
            float ms = 0.f;
            for (int s2 = 0; s2 < S; ++s2) ms += mask[b * S + s2];
            float len = ms < 1.f ? 1.f : ms;
            hmean[b * HD + h] = (red[0][hl] + red[1][hl] + red[2][hl] + red[3][hl]) / len;
        }
    } else {
        // ---- EW[w][r] ----
        int w = bid - 752;
        int r = tid;
        float acc = 0.f;
        for (int k = 0; k < 32; ++k)
            acc += W_width[w * 32 + k] * Wspan[(size_t)(2304 + k) * RR + r];
        EW[w * RR + r] = acc;
    }
}

// =============== k_mid: split-K GEMM (768 blocks) | null heads (64 blocks) ===============
// GEMM: 64x64 tile, K halves of 384. P layout: P[kh*1572864 + c*524288 + m*256 + r]
__global__ __launch_bounds__(256) void k_mid(const ushort* __restrict__ Hb,
                                             const ushort* __restrict__ Wt,
                                             float* __restrict__ P,
                                             const float* __restrict__ hmean,
                                             const float* __restrict__ W_nasp,
                                             const float* __restrict__ b_nasp,
                                             const float* __restrict__ W_nopn,
                                             const float* __restrict__ b_nopn,
                                             float* __restrict__ out_nasp,
                                             float* __restrict__ out_nopn) {
    __shared__ __align__(16) char smem[16384];
    int bid = blockIdx.x;
    int tid = threadIdx.x;

    if (bid < 768) {
        char* ldsA = smem;
        char* ldsB = smem + 8192;
        int mt = bid & 31, nt = (bid >> 5) % 12, kh = bid / 384;
        int m0 = mt * 64, n0 = nt * 64;
        int kbeg = kh * 384;
        int wv = tid >> 6, lane = tid & 63;
        int wm = (wv >> 1) * 32, wn = (wv & 1) * 32;

        f32x4 acc[2][2] = {};

        for (int k0 = kbeg; k0 < kbeg + 384; k0 += 64) {
            #pragma unroll
            for (int i = 0; i < 2; ++i) {
                int c8 = tid * 2 + i;
                int row = c8 >> 3;
                int sw = ((c8 & 7) * 16) ^ ((row & 7) << 4);
                bf16x8 va = *(const bf16x8*)(Hb + (size_t)(m0 + row) * HD + k0 + (c8 & 7) * 8);
                *(bf16x8*)(ldsA + row * 128 + sw) = va;
                bf16x8 vb = *(const bf16x8*)(Wt + (size_t)(n0 + row) * HD + k0 + (c8 & 7) * 8);
                *(bf16x8*)(ldsB + row * 128 + sw) = vb;
            }
            __syncthreads();
            #pragma unroll
            for (int ks = 0; ks < 2; ++ks) {
                int kb = ks * 64 + ((lane >> 4) * 16);
                bf16x8 af[2], bfr[2];
                #pragma unroll
                for (int f = 0; f < 2; ++f) {
                    int ar = wm + f * 16 + (lane & 15);
                    af[f] = *(const bf16x8*)(ldsA + ar * 128 + (kb ^ ((ar & 7) << 4)));
                    int br = wn + f * 16 + (lane & 15);
                    bfr[f] = *(const bf16x8*)(ldsB + br * 128 + (kb ^ ((br & 7) << 4)));
                }
                #pragma unroll
                for (int f = 0; f < 2; ++f)
                    #pragma unroll
                    for (int j = 0; j < 2; ++j)
                        acc[f][j] = __builtin_amdgcn_mfma_f32_16x16x32_bf16(af[f], bfr[j], acc[f][j], 0, 0, 0);
            }
            __syncthreads();
        }

        size_t khoff = (size_t)kh * 1572864;
        #pragma unroll
        for (int f = 0; f < 2; ++f) {
            #pragma unroll
            for (int j = 0; j < 2; ++j) {
                int col = n0 + wn + j * 16 + (lane & 15);
                size_t pb = khoff + (size_t)(col >> 8) * 524288 + (col & 255);
                #pragma unroll
                for (int rg = 0; rg < 4; ++rg) {
                    int row = m0 + wm + f * 16 + (lane >> 4) * 4 + rg;
                    P[pb + (size_t)row * 256] = acc[f][j][rg];
                }
            }
        }
    } else {
        // ---- null heads: 64 blocks, b = idx>>3, rc = idx&7 ----
        float* hm = (float*)smem;                 // 768 f
        float (*ra)[32] = (float(*)[32])(smem + 4096);
        float (*ro)[32] = (float(*)[32])(smem + 5120);
        int idx = bid - 768;
        int b = idx >> 3, rc = idx & 7;
        int c = tid & 31, hc = tid >> 5;
        int r = rc * 32 + c;
        for (int h = tid; h < HD; h += 256) hm[h] = hmean[b * HD + h];
        __syncthreads();
        float a = 0.f, o = 0.f;
        for (int h = hc * 96; h < hc * 96 + 96; ++h) {
            float x = hm[h];
            a += x * W_nasp[(size_t)h * RR + r];
            o += x * W_nopn[(size_t)h * RR + r];
        }
        ra[hc][c] = a; ro[hc][c] = o;
        __syncthreads();
        if (tid < 32) {
            float sa = 0.f, so = 0.f;
            #pragma unroll
            for (int u = 0; u < 8; ++u) { sa += ra[u][tid]; so += ro[u][tid]; }
            int rr = rc * 32 + tid;
            out_nasp[b * RR + rr] = tanhf(sa + b_nasp[rr]);
            out_nopn[b * RR + rr] = tanhf(so + b_nopn[rr]);
        }
    }
}

// =============== k_span3: one block per (b,start); sums split-K P halves ===============
__global__ __launch_bounds__(256) void k_span3(const float* __restrict__ logits,
                                               const float* __restrict__ P,
                                               const float* __restrict__ EW,
                                               const float* __restrict__ b_span,
                                               const float* __restrict__ w_asp,
                                               const float* __restrict__ b_asp,
                                               const float* __restrict__ w_opn,
                                               const float* __restrict__ b_opn,
                                               float* __restrict__ out_repr,
                                               float* __restrict__ out_asp,
                                               float* __restrict__ out_opn) {
    int start = blockIdx.x;
    int b = blockIdx.y;
    int nw = 256 - start; if (nw > 8) nw = 8;
    int r = threadIdx.x;

    int nbase;
    if (start <= 248) nbase = start * 8;
    else { int t = start - 249; nbase = 1992 + 7 * t - (t * (t - 1)) / 2; }

    float E[8], inv[8];
    {
        float lg[8];
        float M = -INFINITY;
        for (int l = 0; l < nw; ++l) {
            lg[l] = logits[b * S + start + l];
            M = fmaxf(M, lg[l]);
        }
        float run = 0.f;
        for (int l = 0; l < nw; ++l) {
            E[l] = __expf(lg[l] - M);
            run += E[l];
            inv[l] = 1.f / run;
        }
    }

    const float* PA = P;              // K-half 0
    const float* PB = P + 1572864;    // K-half 1
    size_t base = ((size_t)b * S + start) * RR + r;

    float p0 = PA[base] + PB[base];
    float bs = b_span[r];
    float num = 0.f;

    __shared__ float vbuf[8][256];

    for (int j = 0; j < nw; ++j) {
        size_t o2 = base + 1048576 + (size_t)j * RR;
        num += E[j] * (PA[o2] + PB[o2]);
        size_t o1 = base + 524288 + (size_t)j * RR;
        float pre = p0 + (PA[o1] + PB[o1]) + num * inv[j]
                  + EW[(j + 1) * RR + r] + bs;
        float v = fmaxf(pre, 0.f);
        vbuf[j][r] = v;
        out_repr[((size_t)b * NSPAN + nbase + j) * RR + r] = v;
    }
    __syncthreads();

    int j = r >> 5, c = r & 31;
    if (j < nw) {
        float pa = 0.f, po = 0.f;
        #pragma unroll
        for (int u = 0; u < 8; ++u) {
            int rr = u * 32 + c;
            float v = vbuf[j][rr];
            pa += v * w_asp[rr];
            po += v * w_opn[rr];
        }
        #pragma unroll
        for (int off = 16; off; off >>= 1) {
            pa += __shfl_down(pa, off, 32);
            po += __shfl_down(po, off, 32);
        }
        if (c == 0) {
            size_t oi = (size_t)b * NSPAN + nbase + j;
            out_asp[oi] = pa + b_asp[0];
            out_opn[oi] = po + b_opn[0];
        }
    }
}

extern "C" void kernel_launch(void* const* d_in, const int* in_sizes, int n_in,
                              void* d_out, int out_size, void* d_ws, size_t ws_size,
                              hipStream_t stream) {
    const float* H       = (const float*)d_in[0];
    const float* mask    = (const float*)d_in[1];
    const float* W_width = (const float*)d_in[2];
    const float* w_attn  = (const float*)d_in[3];
    const float* b_attn  = (const float*)d_in[4];
    const float* W_span  = (const float*)d_in[5];
    const float* b_span  = (const float*)d_in[6];
    const float* w_asp   = (const float*)d_in[7];
    const float* b_asp   = (const float*)d_in[8];
    const float* w_opn   = (const float*)d_in[9];
    const float* b_opn   = (const float*)d_in[10];
    const float* W_nasp  = (const float*)d_in[11];
    const float* b_nasp  = (const float*)d_in[12];
    const float* W_nopn  = (const float*)d_in[13];
    const float* b_nopn  = (const float*)d_in[14];

    float* out  = (float*)d_out;
    float* repr = out;
    float* asp  = out + (size_t)BB * NSPAN * RR;
    float* opn  = asp + (size_t)BB * NSPAN;
    float* nasp = opn + (size_t)BB * NSPAN;
    float* nopn = nasp + (size_t)BB * RR;

    float* ws     = (float*)d_ws;
    float* logits = ws;                 // 2048
    float* hmean  = ws + 2048;          // 6144
    float* EW     = ws + 8192;          // 2304
    float* P      = ws + 10496;         // 2 * 3 * 524288 fp32 (split-K halves)
    ushort* Hb    = (ushort*)(P + 3145728);     // 2048*768 bf16
    ushort* Wt    = Hb + (size_t)2048 * 768;    // 768*768 bf16

    k_pre<<<dim3(761), dim3(256), 0, stream>>>(H, w_attn, b_attn, mask, W_span, W_width,
                                               Hb, logits, Wt, hmean, EW);
    k_mid<<<dim3(832), dim3(256), 0, stream>>>(Hb, Wt, P, hmean,
                                               W_nasp, b_nasp, W_nopn, b_nopn, nasp, nopn);
    k_span3<<<dim3(S, BB), dim3(256), 0, stream>>>(logits, P, EW, b_span, w_asp, b_asp,
                                                   w_opn, b_opn, repr, asp, opn);
}

// Round 6
// 51.688 us; speedup vs baseline: 5.2956x; 1.1165x over previous
//
#include <hip/hip_runtime.h>
#include <math.h>

#define S 256
#define HD 768
#define RR 256
#define NSPAN 2020
#define BB 8

typedef __attribute__((ext_vector_type(8))) short bf16x8;
typedef __attribute__((ext_vector_type(4))) float f32x4;

__device__ inline ushort f2bf(float x) {
    union { float f; unsigned u; } v; v.f = x;
    unsigned r = v.u + 0x7FFF + ((v.u >> 16) & 1);
    return (ushort)(r >> 16);
}

// =============== k_pre: fused prep(512) | cvtW(144) | hmean(96) | EW(9) ===============
__global__ __launch_bounds__(256) void k_pre(const float* __restrict__ H,
                                             const float* __restrict__ w_attn,
                                             const float* __restrict__ b_attn,
                                             const float* __restrict__ mask,
                                             const float* __restrict__ Wspan,
                                             const float* __restrict__ W_width,
                                             ushort* __restrict__ Hb,
                                             float* __restrict__ logits,
                                             ushort* __restrict__ Wt,
                                             float* __restrict__ hmean,
                                             float* __restrict__ EW) {
    __shared__ __align__(16) char smem[16640];
    int bid = blockIdx.x;
    int tid = threadIdx.x;

    if (bid < 512) {
        // ---- prep: H -> bf16 + logits (4 rows/block, 1 wave each) ----
        int wv = tid >> 6, lane = tid & 63;
        int row = bid * 4 + wv;
        const float4* h4 = (const float4*)(H + (size_t)row * HD);
        const float4* w4 = (const float4*)w_attn;
        float acc = 0.f;
        #pragma unroll
        for (int k = 0; k < 3; ++k) {
            float4 a = h4[k * 64 + lane];
            float4 w = w4[k * 64 + lane];
            acc += a.x * w.x + a.y * w.y + a.z * w.z + a.w * w.w;
            ushort4 o;
            o.x = f2bf(a.x); o.y = f2bf(a.y); o.z = f2bf(a.z); o.w = f2bf(a.w);
            *(ushort4*)(Hb + (size_t)row * HD + k * 256 + lane * 4) = o;
        }
        for (int off = 32; off; off >>= 1) acc += __shfl_down(acc, off);
        if (lane == 0) logits[row] = acc + b_attn[0];
    } else if (bid < 656) {
        // ---- cvtW: W_span[0:2304] -> Wt[n][h] bf16 transposed ----
        float (*tile)[65] = (float(*)[65])smem;
        int idx = bid - 512;
        int hb = idx % 12, rb = (idx / 12) & 3, c = idx / 48;
        for (int e = tid; e < 4096; e += 256) {
            int hl = e >> 6, rl = e & 63;
            tile[hl][rl] = Wspan[(size_t)(c * 768 + hb * 64 + hl) * 256 + rb * 64 + rl];
        }
        __syncthreads();
        for (int e = tid; e < 4096; e += 256) {
            int rl = e >> 6, hl = e & 63;
            Wt[(size_t)(c * 256 + rb * 64 + rl) * 768 + hb * 64 + hl] = f2bf(tile[hl][rl]);
        }
    } else if (bid < 752) {
        // ---- hmean: block-parallel mask reduce + strided H accumulate ----
        float (*red)[64] = (float(*)[64])smem;             // 1 KB
        float* msum = (float*)(smem + 1024);               // 4 floats
        int idx = bid - 656;
        int b = idx & 7, hb = idx >> 3;
        int sg = tid >> 6, hl = tid & 63;
        int h = hb * 64 + hl;
        float acc = 0.f;
        for (int s2 = sg; s2 < S; s2 += 4)
            acc += H[((size_t)b * S + s2) * HD + h] * mask[b * S + s2];
        // parallel mask sum: 256 threads, one value each
        float mv = mask[b * S + tid];
        for (int off = 32; off; off >>= 1) mv += __shfl_down(mv, off);
        if (hl == 0) msum[sg] = mv;
        red[sg][hl] = acc;
        __syncthreads();
        if (sg == 0) {
            float ms = msum[0] + msum[1] + msum[2] + msum[3];
            float len = ms < 1.f ? 1.f : ms;
            hmean[b * HD + h] = (red[0][hl] + red[1][hl] + red[2][hl] + red[3][hl]) / len;
        }
    } else {
        // ---- EW[w][r] ----
        int w = bid - 752;
        int r = tid;
        float acc = 0.f;
        for (int k = 0; k < 32; ++k)
            acc += W_width[w * 32 + k] * Wspan[(size_t)(2304 + k) * RR + r];
        EW[w * RR + r] = acc;
    }
}

// =============== k_mid: GEMM 32x64 full-K (768 blocks) | null heads (64 blocks) ===============
// P layout: P[c*524288 + m*256 + r], c = col>>8
__global__ __launch_bounds__(256) void k_mid(const ushort* __restrict__ Hb,
                                             const ushort* __restrict__ Wt,
                                             float* __restrict__ P,
                                             const float* __restrict__ hmean,
                                             const float* __restrict__ W_nasp,
                                             const float* __restrict__ b_nasp,
                                             const float* __restrict__ W_nopn,
                                             const float* __restrict__ b_nopn,
                                             float* __restrict__ out_nasp,
                                             float* __restrict__ out_nopn) {
    __shared__ __align__(16) char smem[12288];
    int bid = blockIdx.x;
    int tid = threadIdx.x;

    if (bid < 768) {
        char* ldsA = smem;            // 32 rows * 128 B = 4 KB
        char* ldsB = smem + 4096;     // 64 rows * 128 B = 8 KB
        int mt = bid & 63, nt = bid >> 6;
        int m0 = mt * 32, n0 = nt * 64;
        int wv = tid >> 6, lane = tid & 63;
        int wm = (wv >> 1) * 16, wn = (wv & 1) * 32;

        f32x4 acc[2] = {};

        for (int k0 = 0; k0 < HD; k0 += 64) {
            {   // A: 256 chunks, 1 per thread
                int row = tid >> 3, ck = tid & 7;
                int sw = (ck * 16) ^ ((row & 7) << 4);
                bf16x8 va = *(const bf16x8*)(Hb + (size_t)(m0 + row) * HD + k0 + ck * 8);
                *(bf16x8*)(ldsA + row * 128 + sw) = va;
            }
            #pragma unroll
            for (int i = 0; i < 2; ++i) {   // B: 512 chunks, 2 per thread
                int c8 = tid * 2 + i;
                int row = c8 >> 3, ck = c8 & 7;
                int sw = (ck * 16) ^ ((row & 7) << 4);
                bf16x8 vb = *(const bf16x8*)(Wt + (size_t)(n0 + row) * HD + k0 + ck * 8);
                *(bf16x8*)(ldsB + row * 128 + sw) = vb;
            }
            __syncthreads();
            #pragma unroll
            for (int ks = 0; ks < 2; ++ks) {
                int kb = ks * 64 + ((lane >> 4) * 16);
                int ar = wm + (lane & 15);
                bf16x8 af = *(const bf16x8*)(ldsA + ar * 128 + (kb ^ ((ar & 7) << 4)));
                bf16x8 bfr[2];
                #pragma unroll
                for (int j = 0; j < 2; ++j) {
                    int br = wn + j * 16 + (lane & 15);
                    bfr[j] = *(const bf16x8*)(ldsB + br * 128 + (kb ^ ((br & 7) << 4)));
                }
                #pragma unroll
                for (int j = 0; j < 2; ++j)
                    acc[j] = __builtin_amdgcn_mfma_f32_16x16x32_bf16(af, bfr[j], acc[j], 0, 0, 0);
            }
            __syncthreads();
        }

        #pragma unroll
        for (int j = 0; j < 2; ++j) {
            int col = n0 + wn + j * 16 + (lane & 15);
            size_t pb = (size_t)(col >> 8) * 524288 + (col & 255);
            #pragma unroll
            for (int rg = 0; rg < 4; ++rg) {
                int row = m0 + wm + (lane >> 4) * 4 + rg;
                P[pb + (size_t)row * 256] = acc[j][rg];
            }
        }
    } else {
        // ---- null heads: 64 blocks ----
        float* hm = (float*)smem;
        float (*ra)[32] = (float(*)[32])(smem + 4096);
        float (*ro)[32] = (float(*)[32])(smem + 5120);
        int idx = bid - 768;
        int b = idx >> 3, rc = idx & 7;
        int c = tid & 31, hc = tid >> 5;
        int r = rc * 32 + c;
        for (int h = tid; h < HD; h += 256) hm[h] = hmean[b * HD + h];
        __syncthreads();
        float a = 0.f, o = 0.f;
        for (int h = hc * 96; h < hc * 96 + 96; ++h) {
            float x = hm[h];
            a += x * W_nasp[(size_t)h * RR + r];
            o += x * W_nopn[(size_t)h * RR + r];
        }
        ra[hc][c] = a; ro[hc][c] = o;
        __syncthreads();
        if (tid < 32) {
            float sa = 0.f, so = 0.f;
            #pragma unroll
            for (int u = 0; u < 8; ++u) { sa += ra[u][tid]; so += ro[u][tid]; }
            int rr = rc * 32 + tid;
            out_nasp[b * RR + rr] = tanhf(sa + b_nasp[rr]);
            out_nopn[b * RR + rr] = tanhf(so + b_nopn[rr]);
        }
    }
}

// =============== k_span3: one block per (b,start) ===============
__global__ __launch_bounds__(256) void k_span3(const float* __restrict__ logits,
                                               const float* __restrict__ P,
                                               const float* __restrict__ EW,
                                               const float* __restrict__ b_span,
                                               const float* __restrict__ w_asp,
                                               const float* __restrict__ b_asp,
                                               const float* __restrict__ w_opn,
                                               const float* __restrict__ b_opn,
                                               float* __restrict__ out_repr,
                                               float* __restrict__ out_asp,
                                               float* __restrict__ out_opn) {
    int start = blockIdx.x;
    int b = blockIdx.y;
    int nw = 256 - start; if (nw > 8) nw = 8;
    int r = threadIdx.x;

    int nbase;
    if (start <= 248) nbase = start * 8;
    else { int t = start - 249; nbase = 1992 + 7 * t - (t * (t - 1)) / 2; }

    float E[8], inv[8];
    {
        float lg[8];
        float M = -INFINITY;
        for (int l = 0; l < nw; ++l) {
            lg[l] = logits[b * S + start + l];
            M = fmaxf(M, lg[l]);
        }
        float run = 0.f;
        for (int l = 0; l < nw; ++l) {
            E[l] = __expf(lg[l] - M);
            run += E[l];
            inv[l] = 1.f / run;
        }
    }

    const float* P0 = P;
    const float* P1 = P + 524288;
    const float* P2 = P + 2 * 524288;
    size_t base = ((size_t)b * S + start) * RR + r;

    float p0 = P0[base];
    float bs = b_span[r];
    float num = 0.f;

    __shared__ float vbuf[8][256];

    for (int j = 0; j < nw; ++j) {
        num += E[j] * P2[base + (size_t)j * RR];
        float pre = p0 + P1[base + (size_t)j * RR] + num * inv[j]
                  + EW[(j + 1) * RR + r] + bs;
        float v = fmaxf(pre, 0.f);
        vbuf[j][r] = v;
        out_repr[((size_t)b * NSPAN + nbase + j) * RR + r] = v;
    }
    __syncthreads();

    int j = r >> 5, c = r & 31;
    if (j < nw) {
        float pa = 0.f, po = 0.f;
        #pragma unroll
        for (int u = 0; u < 8; ++u) {
            int rr = u * 32 + c;
            float v = vbuf[j][rr];
            pa += v * w_asp[rr];
            po += v * w_opn[rr];
        }
        #pragma unroll
        for (int off = 16; off; off >>= 1) {
            pa += __shfl_down(pa, off, 32);
            po += __shfl_down(po, off, 32);
        }
        if (c == 0) {
            size_t oi = (size_t)b * NSPAN + nbase + j;
            out_asp[oi] = pa + b_asp[0];
            out_opn[oi] = po + b_opn[0];
        }
    }
}

extern "C" void kernel_launch(void* const* d_in, const int* in_sizes, int n_in,
                              void* d_out, int out_size, void* d_ws, size_t ws_size,
                              hipStream_t stream) {
    const float* H       = (const float*)d_in[0];
    const float* mask    = (const float*)d_in[1];
    const float* W_width = (const float*)d_in[2];
    const float* w_attn  = (const float*)d_in[3];
    const float* b_attn  = (const float*)d_in[4];
    const float* W_span  = (const float*)d_in[5];
    const float* b_span  = (const float*)d_in[6];
    const float* w_asp   = (const float*)d_in[7];
    const float* b_asp   = (const float*)d_in[8];
    const float* w_opn   = (const float*)d_in[9];
    const float* b_opn   = (const float*)d_in[10];
    const float* W_nasp  = (const float*)d_in[11];
    const float* b_nasp  = (const float*)d_in[12];
    const float* W_nopn  = (const float*)d_in[13];
    const float* b_nopn  = (const float*)d_in[14];

    float* out  = (float*)d_out;
    float* repr = out;
    float* asp  = out + (size_t)BB * NSPAN * RR;
    float* opn  = asp + (size_t)BB * NSPAN;
    float* nasp = opn + (size_t)BB * NSPAN;
    float* nopn = nasp + (size_t)BB * RR;

    float* ws     = (float*)d_ws;
    float* logits = ws;                 // 2048
    float* hmean  = ws + 2048;          // 6144
    float* EW     = ws + 8192;          // 2304
    float* P      = ws + 10496;         // 3 * 524288 fp32
    ushort* Hb    = (ushort*)(P + 1572864);     // 2048*768 bf16
    ushort* Wt    = Hb + (size_t)2048 * 768;    // 768*768 bf16

    k_pre<<<dim3(761), dim3(256), 0, stream>>>(H, w_attn, b_attn, mask, W_span, W_width,
                                               Hb, logits, Wt, hmean, EW);
    k_mid<<<dim3(832), dim3(256), 0, stream>>>(Hb, Wt, P, hmean,
                                               W_nasp, b_nasp, W_nopn, b_nopn, nasp, nopn);
    k_span3<<<dim3(S, BB), dim3(256), 0, stream>>>(logits, P, EW, b_span, w_asp, b_asp,
                                                   w_opn, b_opn, repr, asp, opn);
}

// Round 7
// 50.331 us; speedup vs baseline: 5.4383x; 1.0270x over previous
//
#include <hip/hip_runtime.h>
#include <math.h>

#define S 256
#define HD 768
#define RR 256
#define NSPAN 2020
#define BB 8

typedef __attribute__((ext_vector_type(8))) short bf16x8;
typedef __attribute__((ext_vector_type(4))) float f32x4;

__device__ inline ushort f2bf(float x) {
    union { float f; unsigned u; } v; v.f = x;
    unsigned r = v.u + 0x7FFF + ((v.u >> 16) & 1);
    return (ushort)(r >> 16);
}

// =============== k_pre: fused prep(512) | cvtW(144) | hmean(96) | EW(9) ===============
__global__ __launch_bounds__(256) void k_pre(const float* __restrict__ H,
                                             const float* __restrict__ w_attn,
                                             const float* __restrict__ b_attn,
                                             const float* __restrict__ mask,
                                             const float* __restrict__ Wspan,
                                             const float* __restrict__ W_width,
                                             ushort* __restrict__ Hb,
                                             float* __restrict__ logits,
                                             ushort* __restrict__ Wt,
                                             float* __restrict__ hmean,
                                             float* __restrict__ EW) {
    __shared__ __align__(16) char smem[16640];
    int bid = blockIdx.x;
    int tid = threadIdx.x;

    if (bid < 512) {
        // ---- prep: H -> bf16 + logits (4 rows/block, 1 wave each) ----
        int wv = tid >> 6, lane = tid & 63;
        int row = bid * 4 + wv;
        const float4* h4 = (const float4*)(H + (size_t)row * HD);
        const float4* w4 = (const float4*)w_attn;
        float acc = 0.f;
        #pragma unroll
        for (int k = 0; k < 3; ++k) {
            float4 a = h4[k * 64 + lane];
            float4 w = w4[k * 64 + lane];
            acc += a.x * w.x + a.y * w.y + a.z * w.z + a.w * w.w;
            ushort4 o;
            o.x = f2bf(a.x); o.y = f2bf(a.y); o.z = f2bf(a.z); o.w = f2bf(a.w);
            *(ushort4*)(Hb + (size_t)row * HD + k * 256 + lane * 4) = o;
        }
        for (int off = 32; off; off >>= 1) acc += __shfl_down(acc, off);
        if (lane == 0) logits[row] = acc + b_attn[0];
    } else if (bid < 656) {
        // ---- cvtW: W_span[0:2304] -> Wt[n][h] bf16 transposed ----
        float (*tile)[65] = (float(*)[65])smem;
        int idx = bid - 512;
        int hb = idx % 12, rb = (idx / 12) & 3, c = idx / 48;
        for (int e = tid; e < 4096; e += 256) {
            int hl = e >> 6, rl = e & 63;
            tile[hl][rl] = Wspan[(size_t)(c * 768 + hb * 64 + hl) * 256 + rb * 64 + rl];
        }
        __syncthreads();
        for (int e = tid; e < 4096; e += 256) {
            int rl = e >> 6, hl = e & 63;
            Wt[(size_t)(c * 256 + rb * 64 + rl) * 768 + hb * 64 + hl] = f2bf(tile[hl][rl]);
        }
    } else if (bid < 752) {
        // ---- hmean: block-parallel mask reduce + strided H accumulate ----
        float (*red)[64] = (float(*)[64])smem;
        float* msum = (float*)(smem + 1024);
        int idx = bid - 656;
        int b = idx & 7, hb = idx >> 3;
        int sg = tid >> 6, hl = tid & 63;
        int h = hb * 64 + hl;
        float acc = 0.f;
        for (int s2 = sg; s2 < S; s2 += 4)
            acc += H[((size_t)b * S + s2) * HD + h] * mask[b * S + s2];
        float mv = mask[b * S + tid];
        for (int off = 32; off; off >>= 1) mv += __shfl_down(mv, off);
        if (hl == 0) msum[sg] = mv;
        red[sg][hl] = acc;
        __syncthreads();
        if (sg == 0) {
            float ms = msum[0] + msum[1] + msum[2] + msum[3];
            float len = ms < 1.f ? 1.f : ms;
            hmean[b * HD + h] = (red[0][hl] + red[1][hl] + red[2][hl] + red[3][hl]) / len;
        }
    } else {
        // ---- EW[w][r] ----
        int w = bid - 752;
        int r = tid;
        float acc = 0.f;
        for (int k = 0; k < 32; ++k)
            acc += W_width[w * 32 + k] * Wspan[(size_t)(2304 + k) * RR + r];
        EW[w * RR + r] = acc;
    }
}

// =============== k_mid: GEMM 64x64 acc[2][2] (384 blocks) | null heads (64 blocks) ===============
// P layout: P[c*524288 + m*256 + r], c = col>>8
__global__ __launch_bounds__(256) void k_mid(const ushort* __restrict__ Hb,
                                             const ushort* __restrict__ Wt,
                                             float* __restrict__ P,
                                             const float* __restrict__ hmean,
                                             const float* __restrict__ W_nasp,
                                             const float* __restrict__ b_nasp,
                                             const float* __restrict__ W_nopn,
                                             const float* __restrict__ b_nopn,
                                             float* __restrict__ out_nasp,
                                             float* __restrict__ out_nopn) {
    __shared__ __align__(16) char smem[16384];
    int bid = blockIdx.x;
    int tid = threadIdx.x;

    if (bid < 384) {
        // combined LDS: rows 0..63 = A (64x64 bf16), rows 64..127 = B
        char* lds = smem;
        int mt = bid & 31, nt = bid >> 5;
        int m0 = mt * 64, n0 = nt * 64;
        int wv = tid >> 6, lane = tid & 63;
        int wm = (wv >> 1) * 32, wn = (wv & 1) * 32;

        int srow = tid >> 1;              // 0..127, wave-uniform A/B split
        int ckb = (tid & 1) * 4;          // chunk base within row

        f32x4 acc[2][2] = {};

        for (int k0 = 0; k0 < HD; k0 += 64) {
            {
                const ushort* src = (srow < 64)
                    ? (Hb + (size_t)(m0 + srow) * HD + k0 + ckb * 8)
                    : (Wt + (size_t)(n0 + srow - 64) * HD + k0 + ckb * 8);
                #pragma unroll
                for (int i = 0; i < 4; ++i) {
                    int ck = ckb + i;
                    int sw = (ck * 16) ^ ((srow & 7) << 4);
                    *(bf16x8*)(lds + srow * 128 + sw) = *(const bf16x8*)(src + i * 8);
                }
            }
            __syncthreads();
            #pragma unroll
            for (int ks = 0; ks < 2; ++ks) {
                int kb = ks * 64 + ((lane >> 4) * 16);
                bf16x8 af[2], bfr[2];
                #pragma unroll
                for (int f = 0; f < 2; ++f) {
                    int ar = wm + f * 16 + (lane & 15);
                    af[f] = *(const bf16x8*)(lds + ar * 128 + (kb ^ ((ar & 7) << 4)));
                    int br = 64 + wn + f * 16 + (lane & 15);
                    bfr[f] = *(const bf16x8*)(lds + br * 128 + (kb ^ ((br & 7) << 4)));
                }
                #pragma unroll
                for (int f = 0; f < 2; ++f)
                    #pragma unroll
                    for (int j = 0; j < 2; ++j)
                        acc[f][j] = __builtin_amdgcn_mfma_f32_16x16x32_bf16(af[f], bfr[j], acc[f][j], 0, 0, 0);
            }
            __syncthreads();
        }

        #pragma unroll
        for (int f = 0; f < 2; ++f) {
            #pragma unroll
            for (int j = 0; j < 2; ++j) {
                int col = n0 + wn + j * 16 + (lane & 15);
                size_t pb = (size_t)(col >> 8) * 524288 + (col & 255);
                #pragma unroll
                for (int rg = 0; rg < 4; ++rg) {
                    int row = m0 + wm + f * 16 + (lane >> 4) * 4 + rg;
                    P[pb + (size_t)row * 256] = acc[f][j][rg];
                }
            }
        }
    } else {
        // ---- null heads: 64 blocks ----
        float* hm = (float*)smem;
        float (*ra)[32] = (float(*)[32])(smem + 4096);
        float (*ro)[32] = (float(*)[32])(smem + 5120);
        int idx = bid - 384;
        int b = idx >> 3, rc = idx & 7;
        int c = tid & 31, hc = tid >> 5;
        int r = rc * 32 + c;
        for (int h = tid; h < HD; h += 256) hm[h] = hmean[b * HD + h];
        __syncthreads();
        float a = 0.f, o = 0.f;
        for (int h = hc * 96; h < hc * 96 + 96; ++h) {
            float x = hm[h];
            a += x * W_nasp[(size_t)h * RR + r];
            o += x * W_nopn[(size_t)h * RR + r];
        }
        ra[hc][c] = a; ro[hc][c] = o;
        __syncthreads();
        if (tid < 32) {
            float sa = 0.f, so = 0.f;
            #pragma unroll
            for (int u = 0; u < 8; ++u) { sa += ra[u][tid]; so += ro[u][tid]; }
            int rr = rc * 32 + tid;
            out_nasp[b * RR + rr] = tanhf(sa + b_nasp[rr]);
            out_nopn[b * RR + rr] = tanhf(so + b_nopn[rr]);
        }
    }
}

// =============== k_span4: one 64-thread block per (b,start), float4 per thread ===============
__global__ __launch_bounds__(64) void k_span4(const float* __restrict__ logits,
                                              const float* __restrict__ P,
                                              const float* __restrict__ EW,
                                              const float* __restrict__ b_span,
                                              const float* __restrict__ w_asp,
                                              const float* __restrict__ b_asp,
                                              const float* __restrict__ w_opn,
                                              const float* __restrict__ b_opn,
                                              float* __restrict__ out_repr,
                                              float* __restrict__ out_asp,
                                              float* __restrict__ out_opn) {
    int start = blockIdx.x;
    int b = blockIdx.y;
    int nw = 256 - start; if (nw > 8) nw = 8;
    int t = threadIdx.x;          // 0..63, cols 4t..4t+3

    int nbase;
    if (start <= 248) nbase = start * 8;
    else { int tt = start - 249; nbase = 1992 + 7 * tt - (tt * (tt - 1)) / 2; }

    float E[8], inv[8];
    {
        float lg[8];
        float M = -INFINITY;
        #pragma unroll
        for (int l = 0; l < 8; ++l) {
            lg[l] = (l < nw) ? logits[b * S + start + l] : -INFINITY;
            M = fmaxf(M, lg[l]);
        }
        float run = 0.f;
        #pragma unroll
        for (int l = 0; l < 8; ++l) {
            E[l] = (l < nw) ? __expf(lg[l] - M) : 0.f;
            run += E[l];
            inv[l] = 1.f / run;
        }
    }

    // float4-unit row base: each P row is 64 float4
    size_t rb = ((size_t)b * S + start) * 64 + t;
    const f32x4* P04 = (const f32x4*)P;
    const f32x4* P14 = (const f32x4*)(P + 524288);
    const f32x4* P24 = (const f32x4*)(P + 1048576);

    f32x4 p0 = P04[rb];
    f32x4 bs = ((const f32x4*)b_span)[t];
    f32x4 wa = ((const f32x4*)w_asp)[t];
    f32x4 wo = ((const f32x4*)w_opn)[t];
    f32x4 num = {0.f, 0.f, 0.f, 0.f};
    float pa[8], po[8];

    #pragma unroll
    for (int j = 0; j < 8; ++j) {
        // speculative loads for j >= nw stay inside d_ws (safe, unused)
        f32x4 p2 = P24[rb + (size_t)j * 64];
        f32x4 p1 = P14[rb + (size_t)j * 64];
        f32x4 ewj = ((const f32x4*)EW)[(j + 1) * 64 + t];
        num += E[j] * p2;
        f32x4 pre = p0 + p1 + num * inv[j] + ewj + bs;
        f32x4 v;
        v[0] = fmaxf(pre[0], 0.f);
        v[1] = fmaxf(pre[1], 0.f);
        v[2] = fmaxf(pre[2], 0.f);
        v[3] = fmaxf(pre[3], 0.f);
        if (j < nw)
            *(f32x4*)(out_repr + ((size_t)b * NSPAN + nbase + j) * RR + t * 4) = v;
        pa[j] = v[0] * wa[0] + v[1] * wa[1] + v[2] * wa[2] + v[3] * wa[3];
        po[j] = v[0] * wo[0] + v[1] * wo[1] + v[2] * wo[2] + v[3] * wo[3];
    }

    #pragma unroll
    for (int j = 0; j < 8; ++j) {
        if (j < nw) {
            float a = pa[j], o = po[j];
            #pragma unroll
            for (int off = 32; off; off >>= 1) {
                a += __shfl_down(a, off);
                o += __shfl_down(o, off);
            }
            if (t == 0) {
                size_t oi = (size_t)b * NSPAN + nbase + j;
                out_asp[oi] = a + b_asp[0];
                out_opn[oi] = o + b_opn[0];
            }
        }
    }
}

extern "C" void kernel_launch(void* const* d_in, const int* in_sizes, int n_in,
                              void* d_out, int out_size, void* d_ws, size_t ws_size,
                              hipStream_t stream) {
    const float* H       = (const float*)d_in[0];
    const float* mask    = (const float*)d_in[1];
    const float* W_width = (const float*)d_in[2];
    const float* w_attn  = (const float*)d_in[3];
    const float* b_attn  = (const float*)d_in[4];
    const float* W_span  = (const float*)d_in[5];
    const float* b_span  = (const float*)d_in[6];
    const float* w_asp   = (const float*)d_in[7];
    const float* b_asp   = (const float*)d_in[8];
    const float* w_opn   = (const float*)d_in[9];
    const float* b_opn   = (const float*)d_in[10];
    const float* W_nasp  = (const float*)d_in[11];
    const float* b_nasp  = (const float*)d_in[12];
    const float* W_nopn  = (const float*)d_in[13];
    const float* b_nopn  = (const float*)d_in[14];

    float* out  = (float*)d_out;
    float* repr = out;
    float* asp  = out + (size_t)BB * NSPAN * RR;
    float* opn  = asp + (size_t)BB * NSPAN;
    float* nasp = opn + (size_t)BB * NSPAN;
    float* nopn = nasp + (size_t)BB * RR;

    float* ws     = (float*)d_ws;
    float* logits = ws;                 // 2048
    float* hmean  = ws + 2048;          // 6144
    float* EW     = ws + 8192;          // 2304
    float* P      = ws + 10496;         // 3 * 524288 fp32
    ushort* Hb    = (ushort*)(P + 1572864);     // 2048*768 bf16
    ushort* Wt    = Hb + (size_t)2048 * 768;    // 768*768 bf16

    k_pre<<<dim3(761), dim3(256), 0, stream>>>(H, w_attn, b_attn, mask, W_span, W_width,
                                               Hb, logits, Wt, hmean, EW);
    k_mid<<<dim3(448), dim3(256), 0, stream>>>(Hb, Wt, P, hmean,
                                               W_nasp, b_nasp, W_nopn, b_nopn, nasp, nopn);
    k_span4<<<dim3(S, BB), dim3(64), 0, stream>>>(logits, P, EW, b_span, w_asp, b_asp,
                                                  w_opn, b_opn, repr, asp, opn);
}